// Round 6
// baseline (59.344 us; speedup 1.0000x reference)
//
#include <hip/hip_runtime.h>
#include <stdint.h>

#define BATCH   8192
#define DIM     512
#define SIM_NEG 25
#define NDOTS   (BATCH * SIM_NEG)      // 204800
#define EPS     1e-8f
#define FP8_SCALE 64.0f                // power of 2; product carries 4096
#define INV_SQ  (1.0f / 4096.0f)

typedef float f32x2 __attribute__((ext_vector_type(2)));

// ---------------- fast path ----------------
// prep: one wave per row. Normalizes BOTH y_pred and y_true rows to fp8 e4m3
// (x64) tables yp8/tn8 (4 MB each), computes margin_base = 1 - cos_pos.
// Also zeroes *out (prep completes before negdot launches on the stream).
__global__ __launch_bounds__(256) void prep8b_kernel(
    const float* __restrict__ y_pred, const float* __restrict__ y_true,
    uint2* __restrict__ yp8, uint2* __restrict__ tn8,
    float* __restrict__ mbase, float* __restrict__ out)
{
    if (blockIdx.x == 0 && threadIdx.x == 0) *out = 0.f;

    const int row  = (blockIdx.x * blockDim.x + threadIdx.x) >> 6;
    const int lane = threadIdx.x & 63;

    const float4* p4 = (const float4*)(y_pred + (size_t)row * DIM);
    const float4* t4 = (const float4*)(y_true + (size_t)row * DIM);
    float4 a0 = p4[lane * 2], a1 = p4[lane * 2 + 1];   // elems lane*8..+7
    float4 b0 = t4[lane * 2], b1 = t4[lane * 2 + 1];

    float sp = a0.x*a0.x + a0.y*a0.y + a0.z*a0.z + a0.w*a0.w
             + a1.x*a1.x + a1.y*a1.y + a1.z*a1.z + a1.w*a1.w;
    float st = b0.x*b0.x + b0.y*b0.y + b0.z*b0.z + b0.w*b0.w
             + b1.x*b1.x + b1.y*b1.y + b1.z*b1.z + b1.w*b1.w;
    float dp = a0.x*b0.x + a0.y*b0.y + a0.z*b0.z + a0.w*b0.w
             + a1.x*b1.x + a1.y*b1.y + a1.z*b1.z + a1.w*b1.w;

    #pragma unroll
    for (int off = 32; off; off >>= 1) {
        sp += __shfl_xor(sp, off);
        st += __shfl_xor(st, off);
        dp += __shfl_xor(dp, off);
    }

    const float np_ = sqrtf(sp), nt_ = sqrtf(st);
    const float scp = FP8_SCALE / np_;                 // Gaussian rows: norms >> 0
    const float sct = FP8_SCALE / nt_;

    unsigned py0 = (unsigned)__builtin_amdgcn_cvt_pk_fp8_f32(a0.x*scp, a0.y*scp, 0, false);
    py0 = (unsigned)__builtin_amdgcn_cvt_pk_fp8_f32(a0.z*scp, a0.w*scp, (int)py0, true);
    unsigned py1 = (unsigned)__builtin_amdgcn_cvt_pk_fp8_f32(a1.x*scp, a1.y*scp, 0, false);
    py1 = (unsigned)__builtin_amdgcn_cvt_pk_fp8_f32(a1.z*scp, a1.w*scp, (int)py1, true);

    unsigned pt0 = (unsigned)__builtin_amdgcn_cvt_pk_fp8_f32(b0.x*sct, b0.y*sct, 0, false);
    pt0 = (unsigned)__builtin_amdgcn_cvt_pk_fp8_f32(b0.z*sct, b0.w*sct, (int)pt0, true);
    unsigned pt1 = (unsigned)__builtin_amdgcn_cvt_pk_fp8_f32(b1.x*sct, b1.y*sct, 0, false);
    pt1 = (unsigned)__builtin_amdgcn_cvt_pk_fp8_f32(b1.z*sct, b1.w*sct, (int)pt1, true);

    uint2 wy; wy.x = py0; wy.y = py1;
    uint2 wt; wt.x = pt0; wt.y = pt1;
    yp8[(size_t)row * 64 + lane] = wy;                 // 512 B/row, coalesced
    tn8[(size_t)row * 64 + lane] = wt;

    if (lane == 0)
        mbase[row] = 1.0f - dp / fmaxf(np_ * nt_, EPS);
}

__device__ __forceinline__ float mac16(uint4 y, uint4 t, float d) {
    #pragma unroll
    for (int k = 0; k < 4; ++k) {
        const unsigned yw = (&y.x)[k], tw = (&t.x)[k];
        const f32x2 ylo = __builtin_amdgcn_cvt_pk_f32_fp8((int)yw, false);
        const f32x2 yhi = __builtin_amdgcn_cvt_pk_f32_fp8((int)yw, true);
        const f32x2 tlo = __builtin_amdgcn_cvt_pk_f32_fp8((int)tw, false);
        const f32x2 thi = __builtin_amdgcn_cvt_pk_f32_fp8((int)tw, true);
        d += ylo.x*tlo.x + ylo.y*tlo.y + yhi.x*thi.x + yhi.y*thi.y;
    }
    return d;
}

// negdot5: quad-per-dot. 204800 dots flattened b-major (t = b*25 + s); each
// 4-lane quad computes one full 512-elem fp8xfp8 dot: 16 independent uint4
// loads (8 tn gather + 8 yp), one waitcnt, 256 MACs, then 2+4 shuffles
// total for quad-sum and wave-sum of the 16 relu terms. 3200 blocks.
__global__ __launch_bounds__(256, 4) void negdot5_kernel(
    const uint8_t* __restrict__ yp8, const uint8_t* __restrict__ tn8,
    const int* __restrict__ perm, const float* __restrict__ mbase,
    float* __restrict__ out)
{
    const int t  = blockIdx.x * 64 + (threadIdx.x >> 2);   // global dot id
    const int ql = threadIdx.x & 3;                        // lane within quad
    const int b  = t / 25;
    const int s  = t - b * 25;

    const int j = perm[s * BATCH + b];                     // gathered row id
    const float mbb = mbase[b];

    const uint4* yrow = (const uint4*)(yp8 + (size_t)b * DIM);
    const uint4* trow = (const uint4*)(tn8 + (size_t)j * DIM);

    // issue all 16 loads (independent; imm offsets c*64 within the row)
    uint4 wy[8], wt[8];
    #pragma unroll
    for (int c = 0; c < 8; ++c) wt[c] = trow[ql + c * 4];
    #pragma unroll
    for (int c = 0; c < 8; ++c) wy[c] = yrow[ql + c * 4];

    float d = 0.f;
    #pragma unroll
    for (int c = 0; c < 8; ++c) d = mac16(wy[c], wt[c], d);

    // quad sum (lane's 128 elems -> full 512-elem dot, uniform in quad)
    d += __shfl_xor(d, 1);
    d += __shfl_xor(d, 2);

    float r = fmaxf(fmaf(d, INV_SQ, mbb), 0.f);            // relu margin term

    // wave sum of the 16 quad terms: xor>=4 maps quad->quad bijectively and
    // r is quad-uniform, so each quad is counted exactly once per class.
    r += __shfl_xor(r, 4);
    r += __shfl_xor(r, 8);
    r += __shfl_xor(r, 16);
    r += __shfl_xor(r, 32);

    __shared__ float wsum[4];
    const int wib = threadIdx.x >> 6;
    if ((threadIdx.x & 63) == 0) wsum[wib] = r;
    __syncthreads();
    if (threadIdx.x == 0) {
        float sm = wsum[0] + wsum[1] + wsum[2] + wsum[3];
        atomicAdd(out, sm * (1.0f / (float)NDOTS));
    }
}

// ---------------- fallback path (f32, needs only 96 KB ws) ----------------
__global__ __launch_bounds__(256) void rownorm_kernel(
    const float* __restrict__ y_pred, const float* __restrict__ y_true,
    float* __restrict__ npred, float* __restrict__ ntrue, float* __restrict__ cpos,
    float* __restrict__ out)
{
    if (blockIdx.x == 0 && threadIdx.x == 0) *out = 0.f;
    const int wave = (blockIdx.x * blockDim.x + threadIdx.x) >> 6;
    const int lane = threadIdx.x & 63;
    if (wave >= BATCH) return;
    const float4* p = (const float4*)(y_pred + (size_t)wave * DIM);
    const float4* t = (const float4*)(y_true + (size_t)wave * DIM);
    float sp = 0.f, st = 0.f, dp = 0.f;
    #pragma unroll
    for (int i = 0; i < 2; ++i) {
        float4 a = p[lane + 64 * i];
        float4 b = t[lane + 64 * i];
        sp += a.x*a.x + a.y*a.y + a.z*a.z + a.w*a.w;
        st += b.x*b.x + b.y*b.y + b.z*b.z + b.w*b.w;
        dp += a.x*b.x + a.y*b.y + a.z*b.z + a.w*b.w;
    }
    #pragma unroll
    for (int off = 32; off; off >>= 1) {
        sp += __shfl_xor(sp, off);
        st += __shfl_xor(st, off);
        dp += __shfl_xor(dp, off);
    }
    if (lane == 0) {
        float np_ = sqrtf(sp), nt_ = sqrtf(st);
        npred[wave] = np_;
        ntrue[wave] = nt_;
        cpos[wave]  = dp / fmaxf(np_ * nt_, EPS);
    }
}

__global__ __launch_bounds__(256) void negdot_kernel(
    const float* __restrict__ y_pred, const float* __restrict__ y_true,
    const int* __restrict__ perm,
    const float* __restrict__ npred, const float* __restrict__ ntrue,
    const float* __restrict__ cpos, float* __restrict__ out)
{
    const int wib  = threadIdx.x >> 6;
    const int lane = threadIdx.x & 63;
    const int b    = blockIdx.x * 4 + wib;
    const float4* p = (const float4*)(y_pred + (size_t)b * DIM);
    const float4 a0 = p[lane];
    const float4 a1 = p[lane + 64];
    const float npb         = npred[b];
    const float margin_base = 1.0f - cpos[b];
    float acc = 0.f;
    #pragma unroll 5
    for (int s = 0; s < SIM_NEG; ++s) {
        int pi = perm[s * BATCH + b];
        pi = __builtin_amdgcn_readfirstlane(pi);
        const float4* t = (const float4*)(y_true + (size_t)pi * DIM);
        float4 b0 = t[lane];
        float4 b1 = t[lane + 64];
        float d = a0.x*b0.x + a0.y*b0.y + a0.z*b0.z + a0.w*b0.w
                + a1.x*b1.x + a1.y*b1.y + a1.z*b1.z + a1.w*b1.w;
        #pragma unroll
        for (int off = 32; off; off >>= 1) d += __shfl_xor(d, off);
        float cn = d / fmaxf(ntrue[pi] * npb, EPS);
        acc += fmaxf(margin_base + cn, 0.f);
    }
    __shared__ float wsum[4];
    if (lane == 0) wsum[wib] = acc;
    __syncthreads();
    if (threadIdx.x == 0) {
        float sm = wsum[0] + wsum[1] + wsum[2] + wsum[3];
        atomicAdd(out, sm * (1.0f / ((float)BATCH * (float)SIM_NEG)));
    }
}

extern "C" void kernel_launch(void* const* d_in, const int* in_sizes, int n_in,
                              void* d_out, int out_size, void* d_ws, size_t ws_size,
                              hipStream_t stream) {
    const float* y_pred = (const float*)d_in[0];
    const float* y_true = (const float*)d_in[1];
    const int*   perm   = (const int*)d_in[2];
    float* out = (float*)d_out;

    const size_t tbl_bytes = (size_t)BATCH * DIM;                  // 4 MB each
    const size_t need      = 2 * tbl_bytes + (size_t)BATCH * sizeof(float);

    if (ws_size >= need) {
        uint8_t* yp8 = (uint8_t*)d_ws;
        uint8_t* tn8 = yp8 + tbl_bytes;
        float* mbase = (float*)(tn8 + tbl_bytes);
        prep8b_kernel<<<BATCH / 4, 256, 0, stream>>>(y_pred, y_true,
                                                     (uint2*)yp8, (uint2*)tn8,
                                                     mbase, out);
        negdot5_kernel<<<NDOTS / 64, 256, 0, stream>>>(yp8, tn8, perm, mbase, out);
    } else {
        float* npred = (float*)d_ws;
        float* ntrue = npred + BATCH;
        float* cpos  = ntrue + BATCH;
        rownorm_kernel<<<BATCH / 4, 256, 0, stream>>>(y_pred, y_true, npred, ntrue, cpos, out);
        negdot_kernel<<<BATCH / 4, 256, 0, stream>>>(y_pred, y_true, perm,
                                                     npred, ntrue, cpos, out);
    }
}

// Round 7
// 31.834 us; speedup vs baseline: 1.8642x; 1.8642x over previous
//
#include <hip/hip_runtime.h>
#include <stdint.h>

#define BATCH   8192
#define DIM     512
#define SIM_NEG 25
#define NDOTS   (BATCH * SIM_NEG)      // 204800
#define EPS     1e-8f
#define FP8_SCALE 64.0f                // power of 2; product carries 4096
#define INV_SQ  (1.0f / 4096.0f)

typedef float    f32x2 __attribute__((ext_vector_type(2)));
typedef unsigned u32x4 __attribute__((ext_vector_type(4)));

// ---------------- fast path ----------------
// prep: one wave per row. Normalizes BOTH y_pred and y_true rows to fp8 e4m3
// (x64) tables yp8/tn8 (4 MB each), computes margin_base = 1 - cos_pos.
// Also zeroes *out (prep completes before negdot launches on the stream).
__global__ __launch_bounds__(256) void prep8b_kernel(
    const float* __restrict__ y_pred, const float* __restrict__ y_true,
    uint2* __restrict__ yp8, uint2* __restrict__ tn8,
    float* __restrict__ mbase, float* __restrict__ out)
{
    if (blockIdx.x == 0 && threadIdx.x == 0) *out = 0.f;

    const int row  = (blockIdx.x * blockDim.x + threadIdx.x) >> 6;
    const int lane = threadIdx.x & 63;

    const float4* p4 = (const float4*)(y_pred + (size_t)row * DIM);
    const float4* t4 = (const float4*)(y_true + (size_t)row * DIM);
    float4 a0 = p4[lane * 2], a1 = p4[lane * 2 + 1];   // elems lane*8..+7
    float4 b0 = t4[lane * 2], b1 = t4[lane * 2 + 1];

    float sp = a0.x*a0.x + a0.y*a0.y + a0.z*a0.z + a0.w*a0.w
             + a1.x*a1.x + a1.y*a1.y + a1.z*a1.z + a1.w*a1.w;
    float st = b0.x*b0.x + b0.y*b0.y + b0.z*b0.z + b0.w*b0.w
             + b1.x*b1.x + b1.y*b1.y + b1.z*b1.z + b1.w*b1.w;
    float dp = a0.x*b0.x + a0.y*b0.y + a0.z*b0.z + a0.w*b0.w
             + a1.x*b1.x + a1.y*b1.y + a1.z*b1.z + a1.w*b1.w;

    #pragma unroll
    for (int off = 32; off; off >>= 1) {
        sp += __shfl_xor(sp, off);
        st += __shfl_xor(st, off);
        dp += __shfl_xor(dp, off);
    }

    const float np_ = sqrtf(sp), nt_ = sqrtf(st);
    const float scp = FP8_SCALE / np_;                 // Gaussian rows: norms >> 0
    const float sct = FP8_SCALE / nt_;

    unsigned py0 = (unsigned)__builtin_amdgcn_cvt_pk_fp8_f32(a0.x*scp, a0.y*scp, 0, false);
    py0 = (unsigned)__builtin_amdgcn_cvt_pk_fp8_f32(a0.z*scp, a0.w*scp, (int)py0, true);
    unsigned py1 = (unsigned)__builtin_amdgcn_cvt_pk_fp8_f32(a1.x*scp, a1.y*scp, 0, false);
    py1 = (unsigned)__builtin_amdgcn_cvt_pk_fp8_f32(a1.z*scp, a1.w*scp, (int)py1, true);

    unsigned pt0 = (unsigned)__builtin_amdgcn_cvt_pk_fp8_f32(b0.x*sct, b0.y*sct, 0, false);
    pt0 = (unsigned)__builtin_amdgcn_cvt_pk_fp8_f32(b0.z*sct, b0.w*sct, (int)pt0, true);
    unsigned pt1 = (unsigned)__builtin_amdgcn_cvt_pk_fp8_f32(b1.x*sct, b1.y*sct, 0, false);
    pt1 = (unsigned)__builtin_amdgcn_cvt_pk_fp8_f32(b1.z*sct, b1.w*sct, (int)pt1, true);

    uint2 wy; wy.x = py0; wy.y = py1;
    uint2 wt; wt.x = pt0; wt.y = pt1;
    yp8[(size_t)row * 64 + lane] = wy;                 // 512 B/row, coalesced
    tn8[(size_t)row * 64 + lane] = wt;

    if (lane == 0)
        mbase[row] = 1.0f - dp / fmaxf(np_ * nt_, EPS);
}

__device__ __forceinline__ float mac16v(u32x4 y, u32x4 t, float d) {
    #pragma unroll
    for (int k = 0; k < 4; ++k) {
        const unsigned yw = y[k], tw = t[k];
        const f32x2 ylo = __builtin_amdgcn_cvt_pk_f32_fp8((int)yw, false);
        const f32x2 yhi = __builtin_amdgcn_cvt_pk_f32_fp8((int)yw, true);
        const f32x2 tlo = __builtin_amdgcn_cvt_pk_f32_fp8((int)tw, false);
        const f32x2 thi = __builtin_amdgcn_cvt_pk_f32_fp8((int)tw, true);
        d += ylo.x*tlo.x + ylo.y*tlo.y + yhi.x*thi.x + yhi.y*thi.y;
    }
    return d;
}

// negdot6: octet-per-dot, s-major (t = s*8192 + b). Each wave owns 64
// consecutive dots (same s, consecutive b): perm/mbase reads coalesced in
// the prologue, yp reads sequential, only tn gathers random. The 8-iter
// loop's VMEM is ALL inline-asm global_load_dwordx4 with explicit
// s_waitcnt vmcnt(8) (2-deep pipeline, 16 loads in flight, never drained
// mid-loop) — the HIP compiler cannot serialize or inject waits.
__global__ __launch_bounds__(256, 2) void negdot6_kernel(
    const uint8_t* __restrict__ yp8, const uint8_t* __restrict__ tn8,
    const int* __restrict__ perm, const float* __restrict__ mbase,
    float* __restrict__ out)
{
    const int wid  = (blockIdx.x * 256 + threadIdx.x) >> 6;   // 0..3199
    const int lane = threadIdx.x & 63;
    const int w8   = lane >> 3;          // octet id in wave (0..7)
    const int o    = lane & 7;           // lane in octet

    const int t0      = wid * 64;        // wave's first dot id; same s for all 64
    const int base_b  = t0 & (BATCH - 1);
    const int t_l     = t0 + lane;

    // prologue: the ONLY compiler-generated vector loads, fully consumed here
    const int   j_l  = perm[t_l];                 // coalesced
    const float mb_l = mbase[t_l & (BATCH - 1)];  // coalesced

    int   j8[8];
    float mb8[8];
    #pragma unroll
    for (int i = 0; i < 8; ++i) {
        j8[i]  = __shfl(j_l,  i * 8 + w8);        // octet i*8+w8's gather row
        mb8[i] = __shfl(mb_l, i * 8 + w8);
    }

    u32x4 TA[2][4], YA[2][4];

#define GLOAD(dst, base, OFS) \
    asm volatile("global_load_dwordx4 %0, %1, off offset:" #OFS \
                 : "=v"(dst) : "v"(base))

#define ISSUE(slot, ii) do {                                                  \
        const char* tb_ = (const char*)tn8 +                                  \
            (((size_t)(unsigned)j8[ii]) << 9) + (o << 4);                     \
        const char* yb_ = (const char*)yp8 +                                  \
            (((size_t)(unsigned)(base_b + (ii) * 8 + w8)) << 9) + (o << 4);   \
        GLOAD(TA[slot][0], tb_, 0);   GLOAD(TA[slot][1], tb_, 128);           \
        GLOAD(TA[slot][2], tb_, 256); GLOAD(TA[slot][3], tb_, 384);           \
        GLOAD(YA[slot][0], yb_, 0);   GLOAD(YA[slot][1], yb_, 128);           \
        GLOAD(YA[slot][2], yb_, 256); GLOAD(YA[slot][3], yb_, 384);           \
    } while (0)

    float acc = 0.f;

#define STEP(slot, ii, WAITN) do {                                            \
        asm volatile("s_waitcnt vmcnt(" #WAITN ")");                          \
        __builtin_amdgcn_sched_barrier(0);                                    \
        float d_ = 0.f;                                                       \
        d_ = mac16v(YA[slot][0], TA[slot][0], d_);                            \
        d_ = mac16v(YA[slot][1], TA[slot][1], d_);                            \
        d_ = mac16v(YA[slot][2], TA[slot][2], d_);                            \
        d_ = mac16v(YA[slot][3], TA[slot][3], d_);                            \
        d_ += __shfl_xor(d_, 1);                                              \
        d_ += __shfl_xor(d_, 2);                                              \
        d_ += __shfl_xor(d_, 4);   /* octet-uniform full dot */               \
        acc += fmaxf(fmaf(d_, INV_SQ, mb8[ii]), 0.f);                         \
    } while (0)

    ISSUE(0, 0);
    ISSUE(1, 1); STEP(0, 0, 8);
    ISSUE(0, 2); STEP(1, 1, 8);
    ISSUE(1, 3); STEP(0, 2, 8);
    ISSUE(0, 4); STEP(1, 3, 8);
    ISSUE(1, 5); STEP(0, 4, 8);
    ISSUE(0, 6); STEP(1, 5, 8);
    ISSUE(1, 7); STEP(0, 6, 8);
    STEP(1, 7, 0);

#undef GLOAD
#undef ISSUE
#undef STEP

    // acc is octet-uniform; xor 8/16/32 sums the 8 octets -> wave total
    acc += __shfl_xor(acc, 8);
    acc += __shfl_xor(acc, 16);
    acc += __shfl_xor(acc, 32);

    __shared__ float wsum[4];
    const int wib = threadIdx.x >> 6;
    if (lane == 0) wsum[wib] = acc;
    __syncthreads();
    if (threadIdx.x == 0) {
        float sm = wsum[0] + wsum[1] + wsum[2] + wsum[3];
        atomicAdd(out, sm * (1.0f / (float)NDOTS));
    }
}

// ---------------- fallback path (f32, needs only 96 KB ws) ----------------
__global__ __launch_bounds__(256) void rownorm_kernel(
    const float* __restrict__ y_pred, const float* __restrict__ y_true,
    float* __restrict__ npred, float* __restrict__ ntrue, float* __restrict__ cpos,
    float* __restrict__ out)
{
    if (blockIdx.x == 0 && threadIdx.x == 0) *out = 0.f;
    const int wave = (blockIdx.x * blockDim.x + threadIdx.x) >> 6;
    const int lane = threadIdx.x & 63;
    if (wave >= BATCH) return;
    const float4* p = (const float4*)(y_pred + (size_t)wave * DIM);
    const float4* t = (const float4*)(y_true + (size_t)wave * DIM);
    float sp = 0.f, st = 0.f, dp = 0.f;
    #pragma unroll
    for (int i = 0; i < 2; ++i) {
        float4 a = p[lane + 64 * i];
        float4 b = t[lane + 64 * i];
        sp += a.x*a.x + a.y*a.y + a.z*a.z + a.w*a.w;
        st += b.x*b.x + b.y*b.y + b.z*b.z + b.w*b.w;
        dp += a.x*b.x + a.y*b.y + a.z*b.z + a.w*b.w;
    }
    #pragma unroll
    for (int off = 32; off; off >>= 1) {
        sp += __shfl_xor(sp, off);
        st += __shfl_xor(st, off);
        dp += __shfl_xor(dp, off);
    }
    if (lane == 0) {
        float np_ = sqrtf(sp), nt_ = sqrtf(st);
        npred[wave] = np_;
        ntrue[wave] = nt_;
        cpos[wave]  = dp / fmaxf(np_ * nt_, EPS);
    }
}

__global__ __launch_bounds__(256) void negdot_kernel(
    const float* __restrict__ y_pred, const float* __restrict__ y_true,
    const int* __restrict__ perm,
    const float* __restrict__ npred, const float* __restrict__ ntrue,
    const float* __restrict__ cpos, float* __restrict__ out)
{
    const int wib  = threadIdx.x >> 6;
    const int lane = threadIdx.x & 63;
    const int b    = blockIdx.x * 4 + wib;
    const float4* p = (const float4*)(y_pred + (size_t)b * DIM);
    const float4 a0 = p[lane];
    const float4 a1 = p[lane + 64];
    const float npb         = npred[b];
    const float margin_base = 1.0f - cpos[b];
    float acc = 0.f;
    #pragma unroll 5
    for (int s = 0; s < SIM_NEG; ++s) {
        int pi = perm[s * BATCH + b];
        pi = __builtin_amdgcn_readfirstlane(pi);
        const float4* t = (const float4*)(y_true + (size_t)pi * DIM);
        float4 b0 = t[lane];
        float4 b1 = t[lane + 64];
        float d = a0.x*b0.x + a0.y*b0.y + a0.z*b0.z + a0.w*b0.w
                + a1.x*b1.x + a1.y*b1.y + a1.z*b1.z + a1.w*b1.w;
        #pragma unroll
        for (int off = 32; off; off >>= 1) d += __shfl_xor(d, off);
        float cn = d / fmaxf(ntrue[pi] * npb, EPS);
        acc += fmaxf(margin_base + cn, 0.f);
    }
    __shared__ float wsum[4];
    if (lane == 0) wsum[wib] = acc;
    __syncthreads();
    if (threadIdx.x == 0) {
        float sm = wsum[0] + wsum[1] + wsum[2] + wsum[3];
        atomicAdd(out, sm * (1.0f / ((float)BATCH * (float)SIM_NEG)));
    }
}

extern "C" void kernel_launch(void* const* d_in, const int* in_sizes, int n_in,
                              void* d_out, int out_size, void* d_ws, size_t ws_size,
                              hipStream_t stream) {
    const float* y_pred = (const float*)d_in[0];
    const float* y_true = (const float*)d_in[1];
    const int*   perm   = (const int*)d_in[2];
    float* out = (float*)d_out;

    const size_t tbl_bytes = (size_t)BATCH * DIM;                  // 4 MB each
    const size_t need      = 2 * tbl_bytes + (size_t)BATCH * sizeof(float);

    if (ws_size >= need) {
        uint8_t* yp8 = (uint8_t*)d_ws;
        uint8_t* tn8 = yp8 + tbl_bytes;
        float* mbase = (float*)(tn8 + tbl_bytes);
        prep8b_kernel<<<BATCH / 4, 256, 0, stream>>>(y_pred, y_true,
                                                     (uint2*)yp8, (uint2*)tn8,
                                                     mbase, out);
        negdot6_kernel<<<NDOTS / 256, 256, 0, stream>>>(yp8, tn8, perm, mbase, out);
    } else {
        float* npred = (float*)d_ws;
        float* ntrue = npred + BATCH;
        float* cpos  = ntrue + BATCH;
        rownorm_kernel<<<BATCH / 4, 256, 0, stream>>>(y_pred, y_true, npred, ntrue, cpos, out);
        negdot_kernel<<<BATCH / 4, 256, 0, stream>>>(y_pred, y_true, perm,
                                                     npred, ntrue, cpos, out);
    }
}